// Round 2
// baseline (933.315 us; speedup 1.0000x reference)
//
#include <hip/hip_runtime.h>

#define NB 32      // batches
#define MM 448
#define CC 384
#define SS 512
#define KNN 8
#define NBLK 512u  // fused-kernel grid; co-residency proven: LDS 38.4K (4/CU), VGPR<=256 (2/CU)

// workspace byte offsets
#define WS_IDX    0u            // int   idx[32][512][8]   = 512 KB
#define WS_H1     524288u       // float h1[32][512][64]   = 4 MB
#define WS_PMAX   4718592u      // float pmax[32*16][128]  = 256 KB
#define WS_VV     4980736u      // float vv[32][384]       = 48 KB
#define WS_Y      5029888u      // float y[32][1024]       = 128 KB
#define WS_XCAT   5160960u      // float xcat[32][1408]    = 176 KB (g2 | q)
#define WS_BASEP  5341184u      // float basep[32][384]    = 48 KB
#define WS_BAR    5390336u      // unsigned bar[6*16]      = 384 B (64B-strided counters)

__device__ __forceinline__ float wave_sum(float v) {
#pragma unroll
  for (int m = 1; m < 64; m <<= 1) v += __shfl_xor(v, m, 64);
  return v;
}

// device-scope grid barrier: one-shot counter per phase (re-zeroed by K1 each launch).
// NOT cooperative-launch-dependent -> safe under hipGraph capture/replay.
__device__ __forceinline__ void gbar(unsigned* c) {
  __threadfence();              // release my block's global writes (wb L2, device scope)
  __syncthreads();
  if (threadIdx.x == 0) {
    __hip_atomic_fetch_add(c, 1u, __ATOMIC_RELEASE, __HIP_MEMORY_SCOPE_AGENT);
    long spins = 0;
    unsigned v;
    do {
      v = __hip_atomic_load(c, __ATOMIC_ACQUIRE, __HIP_MEMORY_SCOPE_AGENT);
      if (v >= NBLK) break;
      __builtin_amdgcn_s_sleep(1);
    } while (++spins < (1L << 27));   // failsafe: wrong answer beats a hung container
  }
  __syncthreads();
  __threadfence();              // acquire: invalidate stale L1/L2 before consuming
}

// ------------------------------------------------- K1: KNN + gc1, wave-per-point
__global__ __launch_bounds__(256) void k_knn_gc1(
    const float* __restrict__ skel,
    const float* __restrict__ w1root, const float* __restrict__ w1rel,
    const float* __restrict__ b1,
    int* __restrict__ idx_ws, float* __restrict__ h1_ws,
    unsigned* __restrict__ bar)
{
  // arm the fused kernel's barrier counters (stream order guarantees visibility)
  if (blockIdx.x == 0 && threadIdx.x < 6) bar[threadIdx.x * 16] = 0u;

  int b   = blockIdx.x >> 7;          // 128 groups of 4 points per batch
  int grp = blockIdx.x & 127;
  __shared__ __align__(16) float4 sk[SS];
  const float* sb = skel + b * SS * 3;
  for (int t = threadIdx.x; t < SS; t += 256)
    sk[t] = make_float4(sb[t*3+0], sb[t*3+1], sb[t*3+2], 0.f);
  __syncthreads();

  int wave = threadIdx.x >> 6, lane = threadIdx.x & 63;
  int i = grp * 4 + wave;             // this wave's point
  float4 pi = sk[i];

  float bd[KNN];
#pragma unroll
  for (int t = 0; t < KNN; t++) {
    int j = lane + (t << 6);
    float4 p = sk[j];
    float d2;
    {
#pragma clang fp contract(off)
      float dx = pi.x - p.x, dy = pi.y - p.y, dz = pi.z - p.z;
      d2 = (dx*dx + dy*dy) + dz*dz;
    }
    bd[t] = (j == i) ? 3e38f : d2;
  }

  int win[KNN];
  int* idx_base = idx_ws + (size_t)(b*SS + i) * KNN;
#pragma unroll
  for (int t = 0; t < KNN; t++) {
    float bestd = bd[0]; int bests = 0;
#pragma unroll
    for (int s = 1; s < KNN; s++)
      if (bd[s] < bestd) { bestd = bd[s]; bests = s; }
    int bestj = lane + (bests << 6);
#pragma unroll
    for (int m = 1; m < 64; m <<= 1) {
      float od = __shfl_xor(bestd, m, 64);
      int   oj = __shfl_xor(bestj, m, 64);
      if (od < bestd || (od == bestd && oj < bestj)) { bestd = od; bestj = oj; }
    }
    win[t] = bestj;
    if (lane == t) idx_base[t] = bestj;
    if ((bestj & 63) == lane) {
      int sl = bestj >> 6;
#pragma unroll
      for (int s = 0; s < KNN; s++) if (s == sl) bd[s] = 3e38f;
    }
  }

  float a0 = 0.f, a1 = 0.f, a2 = 0.f;
#pragma unroll
  for (int t = 0; t < KNN; t++) {
    float4 n = sk[win[t]];
    a0 += n.x; a1 += n.y; a2 += n.z;
  }

  int c = lane;
  float h = b1[c] + pi.x*w1root[c] + pi.y*w1root[64+c] + pi.z*w1root[128+c]
                  + a0*w1rel[c]   + a1*w1rel[64+c]   + a2*w1rel[128+c];
  h = fmaxf(h, 0.f);
  h1_ws[(size_t)(b*SS + i) * 64 + lane] = h;
}

// =================== K2: everything after KNN+gc1, one kernel, 6 device barriers
struct CoopArgs {
  const float* h1; const int* idx;
  const float *g2wr, *g2wl, *g2b;
  const float *projw, *projb;
  const float *aiw, *aib, *aow, *aob;
  const float *i1w, *i1b, *bng, *bnb, *bnm, *bnv;
  const float *i2w, *i2b;
  const float *redw, *redb;
  const float* coarse;
  float *pmax, *vv, *y, *xcat, *basep, *out;
  unsigned* bar;
};

__global__ __launch_bounds__(256, 2) void k_fused(CoopArgs a)
{
  // 38.4 KB union — max phase is gc2 (X 16.5K + Wt 16K + mred 4K + nbs 1K).
  __shared__ __align__(16) float smem[9600];
  const int t   = threadIdx.x;
  const int blk = blockIdx.x;

  // ---------------- phase 1: gc2 + per-chunk max (512 blocks) ----------------
  {
    int b = blk >> 4, chunk = blk & 15;
    int r0 = chunk * 32;
    float* X    = smem;                  // [32][129]
    float* Wt   = smem + 4128;           // [32][128]
    float* mred = smem + 8224;           // [8][128]
    int*   nbs  = (int*)(smem + 9248);   // [32][8]

    const float* h1b = a.h1 + (size_t)b * SS * 64;
    nbs[t] = a.idx[(b*SS + r0)*KNN + t];
#pragma unroll
    for (int p = 0; p < 8; p++) {
      int idx = t + 256*p;
      int r = idx >> 6, k = idx & 63;
      X[r*129 + k] = h1b[(r0 + r)*64 + k];
    }
    __syncthreads();   // nbs ready
#pragma unroll
    for (int p = 0; p < 8; p++) {
      int idx = t + 256*p;
      int r = idx >> 6, k = idx & 63;
      const int* nb = nbs + r*KNN;
      float s = 0.f;
#pragma unroll
      for (int j = 0; j < KNN; j++) s += h1b[nb[j]*64 + k];
      X[r*129 + 64 + k] = s;
    }

    int rg = t >> 5, cgi = t & 31;
    float acc[4][4];
#pragma unroll
    for (int r = 0; r < 4; r++)
#pragma unroll
      for (int u = 0; u < 4; u++) acc[r][u] = 0.f;

    const float* wsrc[4] = { a.g2wr, a.g2wr + 32*128, a.g2wl, a.g2wl + 32*128 };
#pragma unroll 1
    for (int ch = 0; ch < 4; ch++) {
      __syncthreads();
      const float* ws = wsrc[ch];
#pragma unroll
      for (int p = 0; p < 16; p++) {
        int idx = t + 256*p;
        Wt[idx] = ws[idx];
      }
      __syncthreads();
      int kb = ch * 32;
      const float* xr0 = X + (rg*4+0)*129 + kb;
      const float* xr1 = X + (rg*4+1)*129 + kb;
      const float* xr2 = X + (rg*4+2)*129 + kb;
      const float* xr3 = X + (rg*4+3)*129 + kb;
#pragma unroll 4
      for (int k = 0; k < 32; k++) {
        float4 w4 = *(const float4*)(Wt + k*128 + cgi*4);
        float x0 = xr0[k], x1 = xr1[k], x2 = xr2[k], x3 = xr3[k];
        acc[0][0] += x0*w4.x; acc[0][1] += x0*w4.y; acc[0][2] += x0*w4.z; acc[0][3] += x0*w4.w;
        acc[1][0] += x1*w4.x; acc[1][1] += x1*w4.y; acc[1][2] += x1*w4.z; acc[1][3] += x1*w4.w;
        acc[2][0] += x2*w4.x; acc[2][1] += x2*w4.y; acc[2][2] += x2*w4.z; acc[2][3] += x2*w4.w;
        acc[3][0] += x3*w4.x; acc[3][1] += x3*w4.y; acc[3][2] += x3*w4.z; acc[3][3] += x3*w4.w;
      }
    }
#pragma unroll
    for (int u = 0; u < 4; u++)
      mred[rg*128 + cgi*4 + u] =
        fmaxf(fmaxf(acc[0][u], acc[1][u]), fmaxf(acc[2][u], acc[3][u]));
    __syncthreads();
    if (t < 128) {
      float mx = mred[t];
#pragma unroll
      for (int g = 1; g < 8; g++) mx = fmaxf(mx, mred[g*128 + t]);
      a.pmax[(size_t)(b*16 + chunk)*128 + t] = mx + a.g2b[t];
    }
  }
  gbar(a.bar + 0*16);

  // ------- phase 2: proxy max + kv (in-LDS, dup per block) + vv (384 blocks) --
  if (blk < 384) {
    int b = blk & 31, og = blk >> 5;              // og 0..11
    if (t < 128) {
      float m = -3e38f;
      for (int ch = 0; ch < 16; ch++)
        m = fmaxf(m, a.pmax[(size_t)(b*16 + ch)*128 + t]);
      smem[t] = m;
    }
    __syncthreads();
    // kv (full 384) into smem[128..512); cheap dup across the 12 og-blocks
    for (int o = t; o < CC; o += 256) {
      float acc = a.projb[o];
      for (int s = 0; s < 128; s++) acc += smem[s] * a.projw[s*CC + o];  // coalesced
      smem[128 + o] = acc;
    }
    __syncthreads();
    const float* xs = smem + 128;
    int wv = t >> 6, lane = t & 63;
    float x0 = xs[lane*6+0], x1 = xs[lane*6+1], x2 = xs[lane*6+2];
    float x3 = xs[lane*6+3], x4 = xs[lane*6+4], x5 = xs[lane*6+5];
#pragma unroll
    for (int u = 0; u < 8; u++) {
      int o = og*32 + wv*8 + u;
      const float* wr = a.aiw + (size_t)(2*CC + o) * CC + lane*6;
      float2 wa = *(const float2*)wr;
      float2 wb = *(const float2*)(wr + 2);
      float2 wc = *(const float2*)(wr + 4);
      float p = wa.x*x0 + wa.y*x1 + wb.x*x2 + wb.y*x3 + wc.x*x4 + wc.y*x5;
      p = wave_sum(p);
      if (lane == 0) a.vv[b*CC + o] = a.aib[2*CC + o] + p;
    }
  }
  gbar(a.bar + 1*16);

  // ---------------- phase 3: q = vv @ aow.T + aob -> xcat[:,1024:] -----------
  if (blk < 384) {
    int b = blk & 31, og = blk >> 5;
    for (int i = t; i < CC; i += 256) smem[i] = a.vv[b*CC + i];
    __syncthreads();
    int wv = t >> 6, lane = t & 63;
    float x0 = smem[lane*6+0], x1 = smem[lane*6+1], x2 = smem[lane*6+2];
    float x3 = smem[lane*6+3], x4 = smem[lane*6+4], x5 = smem[lane*6+5];
#pragma unroll
    for (int u = 0; u < 8; u++) {
      int o = og*32 + wv*8 + u;
      const float* wr = a.aow + (size_t)o * CC + lane*6;
      float2 wa = *(const float2*)wr;
      float2 wb = *(const float2*)(wr + 2);
      float2 wc = *(const float2*)(wr + 4);
      float p = wa.x*x0 + wa.y*x1 + wb.x*x2 + wb.y*x3 + wc.x*x4 + wc.y*x5;
      p = wave_sum(p);
      if (lane == 0) a.xcat[b*1408 + 1024 + o] = a.aob[o] + p;
    }
  }
  gbar(a.bar + 2*16);

  // ---------------- phase 4: inc1 + BN + leaky (512 blocks) ------------------
  {
    int b = blk >> 4, og = blk & 15;
    int o = og*64 + (t >> 2), qq = t & 3;
    for (int i = t; i < CC; i += 256) smem[i] = a.xcat[b*1408 + 1024 + i];
    __syncthreads();
    const float* wr = a.i1w + (size_t)o * CC + qq*96;
    const float* xr = smem + qq*96;
    float acc = 0.f;
#pragma unroll
    for (int kk = 0; kk < 96; kk += 4) {
      float4 w4 = *(const float4*)(wr + kk);
      float4 x4 = *(const float4*)(xr + kk);
      acc += w4.x*x4.x + w4.y*x4.y + w4.z*x4.z + w4.w*x4.w;
    }
    acc += __shfl_xor(acc, 1, 64);
    acc += __shfl_xor(acc, 2, 64);
    if (qq == 0) {
      float v = acc + a.i1b[o];
      float z = a.bng[o] * (v - a.bnm[o]) * rsqrtf(a.bnv[o] + 1e-5f) + a.bnb[o];
      a.y[b*1024 + o] = (z >= 0.f) ? z : 0.2f * z;
    }
  }
  gbar(a.bar + 3*16);

  // ---------------- phase 5: inc2 -> xcat[:,0:1024] (512 blocks) -------------
  {
    int b = blk >> 4, og = blk & 15;
    int o = og*64 + (t >> 2), qq = t & 3;
    for (int i = t; i < 1024; i += 256) smem[i] = a.y[b*1024 + i];
    __syncthreads();
    const float* wr = a.i2w + (size_t)o * 1024 + qq*256;
    const float* xr = smem + qq*256;
    float acc = 0.f;
#pragma unroll 8
    for (int kk = 0; kk < 256; kk += 4) {
      float4 w4 = *(const float4*)(wr + kk);
      float4 x4 = *(const float4*)(xr + kk);
      acc += w4.x*x4.x + w4.y*x4.y + w4.z*x4.z + w4.w*x4.w;
    }
    acc += __shfl_xor(acc, 1, 64);
    acc += __shfl_xor(acc, 2, 64);
    if (qq == 0) a.xcat[b*1408 + o] = acc + a.i2b[o];
  }
  gbar(a.bar + 4*16);

  // ---------------- phase 6: basep = xcat @ red_w[:1408] (48 blocks) ---------
  if (blk < 48) {
    int o0 = blk * 8;
    float* xs = smem;           // [32][129] chunk of xcat
    float* wt = smem + 4128;    // [128][8]  chunk of red_w
    int o4 = t & 1, bb = (t >> 1) & 31, kq = t >> 6;
    float acc0 = 0.f, acc1 = 0.f, acc2 = 0.f, acc3 = 0.f;
#pragma unroll 1
    for (int c0 = 0; c0 < 1408; c0 += 128) {
      __syncthreads();
#pragma unroll
      for (int p = 0; p < 16; p++) {
        int idx = t + 256*p;                    // 4096 = 32 b x 128 k
        xs[(idx >> 7)*129 + (idx & 127)] = a.xcat[(idx >> 7)*1408 + c0 + (idx & 127)];
      }
#pragma unroll
      for (int p = 0; p < 4; p++) {
        int idx = t + 256*p;                    // 1024 = 128 k x 8 o
        wt[idx] = a.redw[(size_t)(c0 + (idx >> 3)) * CC + o0 + (idx & 7)];
      }
      __syncthreads();
      const float* xrow = xs + bb*129 + kq*32;  // conflict-free (stride 129)
      const float* wrow = wt + kq*32*8 + o4*4;  // 2 distinct addrs/wave: broadcast
#pragma unroll 8
      for (int i = 0; i < 32; i++) {
        float  x  = xrow[i];
        float4 w4 = *(const float4*)(wrow + i*8);
        acc0 += x*w4.x; acc1 += x*w4.y; acc2 += x*w4.z; acc3 += x*w4.w;
      }
    }
    __syncthreads();
    float* red = smem;          // [256 threads][4]
    red[t*4+0] = acc0; red[t*4+1] = acc1; red[t*4+2] = acc2; red[t*4+3] = acc3;
    __syncthreads();
    {
      int bb2 = t >> 3, oj = t & 7;            // 32 b x 8 o
      float s = 0.f;
#pragma unroll
      for (int k2 = 0; k2 < 4; k2++)
        s += red[(k2*64 + bb2*2 + (oj >> 2))*4 + (oj & 3)];
      a.basep[bb2*CC + o0 + oj] = s;
    }
  }
  gbar(a.bar + 5*16);

  // ---------------- phase 7: out = basep + red_b + coarse @ red_w[1408:] -----
  {
    const int total = NB*MM*96;                 // 32*448*96
    for (int gid = blk*256 + t; gid < total; gid += (int)NBLK*256) {
      int c4 = gid % 96;
      int row = gid / 96;                       // b*448 + m
      int b = row / 448;
      int c = c4 * 4;
      float4 p0 = *(const float4*)(a.basep + b*CC + c);
      float4 rb = *(const float4*)(a.redb + c);
      const float* cr = a.coarse + (size_t)row * 3;
      float cx = cr[0], cy = cr[1], cz = cr[2];
      float4 w0 = *(const float4*)(a.redw + (size_t)1408*CC + c);
      float4 w1 = *(const float4*)(a.redw + (size_t)1409*CC + c);
      float4 w2 = *(const float4*)(a.redw + (size_t)1410*CC + c);
      float4 o4v;
      o4v.x = p0.x + rb.x + cx*w0.x + cy*w1.x + cz*w2.x;
      o4v.y = p0.y + rb.y + cx*w0.y + cy*w1.y + cz*w2.y;
      o4v.z = p0.z + rb.z + cx*w0.z + cy*w1.z + cz*w2.z;
      o4v.w = p0.w + rb.w + cx*w0.w + cy*w1.w + cz*w2.w;
      *(float4*)(a.out + (size_t)row*CC + c) = o4v;
    }
  }
}

extern "C" void kernel_launch(void* const* d_in, const int* in_sizes, int n_in,
                              void* d_out, int out_size, void* d_ws, size_t ws_size,
                              hipStream_t stream)
{
  (void)in_sizes; (void)n_in; (void)out_size; (void)ws_size;
  // d_in[0] is q (B,M,C): provably unused — attention softmax is uniform.
  const float* coarse = (const float*)d_in[1];
  const float* skel   = (const float*)d_in[2];
  const float* g1wr   = (const float*)d_in[3];
  const float* g1wl   = (const float*)d_in[4];
  const float* g1b    = (const float*)d_in[5];

  char* ws = (char*)d_ws;
  int*      idx_ws = (int*)(ws + WS_IDX);
  float*    h1_ws  = (float*)(ws + WS_H1);
  unsigned* bar    = (unsigned*)(ws + WS_BAR);

  CoopArgs a;
  a.h1    = h1_ws;
  a.idx   = idx_ws;
  a.g2wr  = (const float*)d_in[6];
  a.g2wl  = (const float*)d_in[7];
  a.g2b   = (const float*)d_in[8];
  a.projw = (const float*)d_in[9];
  a.projb = (const float*)d_in[10];
  a.aiw   = (const float*)d_in[11];
  a.aib   = (const float*)d_in[12];
  a.aow   = (const float*)d_in[13];
  a.aob   = (const float*)d_in[14];
  a.i1w   = (const float*)d_in[15];
  a.i1b   = (const float*)d_in[16];
  a.bng   = (const float*)d_in[17];
  a.bnb   = (const float*)d_in[18];
  a.bnm   = (const float*)d_in[19];
  a.bnv   = (const float*)d_in[20];
  a.i2w   = (const float*)d_in[21];
  a.i2b   = (const float*)d_in[22];
  a.redw  = (const float*)d_in[23];
  a.redb  = (const float*)d_in[24];
  a.coarse= coarse;
  a.pmax  = (float*)(ws + WS_PMAX);
  a.vv    = (float*)(ws + WS_VV);
  a.y     = (float*)(ws + WS_Y);
  a.xcat  = (float*)(ws + WS_XCAT);
  a.basep = (float*)(ws + WS_BASEP);
  a.out   = (float*)d_out;
  a.bar   = bar;

  k_knn_gc1<<<4096, 256, 0, stream>>>(skel, g1wr, g1wl, g1b, idx_ws, h1_ws, bar);
  k_fused<<<NBLK, 256, 0, stream>>>(a);
}

// Round 3
// 279.226 us; speedup vs baseline: 3.3425x; 3.3425x over previous
//
#include <hip/hip_runtime.h>

#define NB 32      // batches
#define MM 448
#define CC 384
#define SS 512
#define KNN 8
#define NBLK 512u  // fused-kernel grid; co-residency proven by R2 (barrier converged)

// workspace byte offsets
#define WS_IDX    0u            // int   idx[32][512][8]   = 512 KB
#define WS_H1     524288u       // float h1[32][512][64]   = 4 MB
#define WS_PMAX   4718592u      // float pmax[32*16][128]  = 256 KB
#define WS_VV     4980736u      // float vv[32][384]       = 48 KB
#define WS_Y      5029888u      // float y[32][1024]       = 128 KB
#define WS_XCAT   5160960u      // float xcat[32][1408]    = 176 KB (g2 | q)
#define WS_BASEP  5341184u      // float basep[32][384]    = 48 KB
#define WS_BAR    5390336u      // unsigned bar[9*16]: 8 split arrival counters + go word

#define AGENT __HIP_MEMORY_SCOPE_AGENT

// L2-bypass (agent-coherent) scalar load/store: lower to global_load/store sc0 sc1.
// No cache-maintenance instructions -> cheap; always coherent at L3/IF point.
__device__ __forceinline__ float ldg_f(const float* p) {
  return __hip_atomic_load(p, __ATOMIC_RELAXED, AGENT);
}
__device__ __forceinline__ void stg_f(float* p, float v) {
  __hip_atomic_store(p, v, __ATOMIC_RELAXED, AGENT);
}

__device__ __forceinline__ float wave_sum(float v) {
#pragma unroll
  for (int m = 1; m < 64; m <<= 1) v += __shfl_xor(v, m, 64);
  return v;
}

// Fence-free device barrier. All cross-phase data uses sc1-bypass ld/st, so:
//   release = s_waitcnt vmcnt(0) (stores already at coherent point; L2 never dirty)
//   acquire = nothing (readers bypass stale L1/L2)
// Arrival: 8 split counters (64B apart), monotonic target 512*(phase+1).
// Broadcast: block 0 sums counters, then writes go=phase+1; others poll go only.
__device__ __forceinline__ void gbar(unsigned* bar, int phase, int blk) {
  asm volatile("s_waitcnt vmcnt(0)" ::: "memory");  // each wave drains its own stores
  __syncthreads();
  if (threadIdx.x == 0) {
    __hip_atomic_fetch_add(bar + (blk & 7) * 16, 1u, __ATOMIC_RELAXED, AGENT);
    long spins = 0;
    unsigned tgt = (unsigned)(phase + 1);
    if (blk == 0) {
      unsigned target = NBLK * tgt;
      for (;;) {
        unsigned s = 0;
#pragma unroll
        for (int i = 0; i < 8; i++)
          s += __hip_atomic_load(bar + i * 16, __ATOMIC_RELAXED, AGENT);
        if (s >= target) break;
        __builtin_amdgcn_s_sleep(8);
        if (++spins > (1L << 21)) break;   // failsafe: wrong answer beats a hang
      }
      __hip_atomic_store(bar + 8 * 16, tgt, __ATOMIC_RELAXED, AGENT);
    } else {
      while (__hip_atomic_load(bar + 8 * 16, __ATOMIC_RELAXED, AGENT) < tgt) {
        __builtin_amdgcn_s_sleep(8);
        if (++spins > (1L << 21)) break;
      }
    }
  }
  __syncthreads();
}

// ------------------------------------------------- K1: KNN + gc1, wave-per-point
__global__ __launch_bounds__(256) void k_knn_gc1(
    const float* __restrict__ skel,
    const float* __restrict__ w1root, const float* __restrict__ w1rel,
    const float* __restrict__ b1,
    int* __restrict__ idx_ws, float* __restrict__ h1_ws,
    unsigned* __restrict__ bar)
{
  // re-arm the fused kernel's barrier words every launch (stream order publishes)
  if (blockIdx.x == 0 && threadIdx.x < 9) bar[threadIdx.x * 16] = 0u;

  int b   = blockIdx.x >> 7;          // 128 groups of 4 points per batch
  int grp = blockIdx.x & 127;
  __shared__ __align__(16) float4 sk[SS];
  const float* sb = skel + b * SS * 3;
  for (int t = threadIdx.x; t < SS; t += 256)
    sk[t] = make_float4(sb[t*3+0], sb[t*3+1], sb[t*3+2], 0.f);
  __syncthreads();

  int wave = threadIdx.x >> 6, lane = threadIdx.x & 63;
  int i = grp * 4 + wave;             // this wave's point
  float4 pi = sk[i];

  float bd[KNN];
#pragma unroll
  for (int t = 0; t < KNN; t++) {
    int j = lane + (t << 6);
    float4 p = sk[j];
    float d2;
    {
#pragma clang fp contract(off)
      float dx = pi.x - p.x, dy = pi.y - p.y, dz = pi.z - p.z;
      d2 = (dx*dx + dy*dy) + dz*dz;
    }
    bd[t] = (j == i) ? 3e38f : d2;
  }

  int win[KNN];
  int* idx_base = idx_ws + (size_t)(b*SS + i) * KNN;
#pragma unroll
  for (int t = 0; t < KNN; t++) {
    float bestd = bd[0]; int bests = 0;
#pragma unroll
    for (int s = 1; s < KNN; s++)
      if (bd[s] < bestd) { bestd = bd[s]; bests = s; }
    int bestj = lane + (bests << 6);
#pragma unroll
    for (int m = 1; m < 64; m <<= 1) {
      float od = __shfl_xor(bestd, m, 64);
      int   oj = __shfl_xor(bestj, m, 64);
      if (od < bestd || (od == bestd && oj < bestj)) { bestd = od; bestj = oj; }
    }
    win[t] = bestj;
    if (lane == t) idx_base[t] = bestj;
    if ((bestj & 63) == lane) {
      int sl = bestj >> 6;
#pragma unroll
      for (int s = 0; s < KNN; s++) if (s == sl) bd[s] = 3e38f;
    }
  }

  float a0 = 0.f, a1 = 0.f, a2 = 0.f;
#pragma unroll
  for (int t = 0; t < KNN; t++) {
    float4 n = sk[win[t]];
    a0 += n.x; a1 += n.y; a2 += n.z;
  }

  int c = lane;
  float h = b1[c] + pi.x*w1root[c] + pi.y*w1root[64+c] + pi.z*w1root[128+c]
                  + a0*w1rel[c]   + a1*w1rel[64+c]   + a2*w1rel[128+c];
  h = fmaxf(h, 0.f);
  h1_ws[(size_t)(b*SS + i) * 64 + lane] = h;
}

// =================== K2: everything after KNN+gc1, one kernel, 6 device barriers
struct CoopArgs {
  const float* h1; const int* idx;
  const float *g2wr, *g2wl, *g2b;
  const float *projw, *projb;
  const float *aiw, *aib, *aow, *aob;
  const float *i1w, *i1b, *bng, *bnb, *bnm, *bnv;
  const float *i2w, *i2b;
  const float *redw, *redb;
  const float* coarse;
  float *pmax, *vv, *y, *xcat, *basep, *out;
  unsigned* bar;
};

__global__ __launch_bounds__(256, 2) void k_fused(CoopArgs a)
{
  // 38.4 KB union — max phase is gc2 (X 16.5K + Wt 16K + mred 4K + nbs 1K).
  __shared__ __align__(16) float smem[9600];
  const int t   = threadIdx.x;
  const int blk = blockIdx.x;

  // ---------------- phase 1: gc2 + per-chunk max (512 blocks) ----------------
  {
    int b = blk >> 4, chunk = blk & 15;
    int r0 = chunk * 32;
    float* X    = smem;                  // [32][129]
    float* Wt   = smem + 4128;           // [32][128]
    float* mred = smem + 8224;           // [8][128]
    int*   nbs  = (int*)(smem + 9248);   // [32][8]

    const float* h1b = a.h1 + (size_t)b * SS * 64;
    nbs[t] = a.idx[(b*SS + r0)*KNN + t];
#pragma unroll
    for (int p = 0; p < 8; p++) {
      int idx = t + 256*p;
      int r = idx >> 6, k = idx & 63;
      X[r*129 + k] = h1b[(r0 + r)*64 + k];
    }
    __syncthreads();   // nbs ready
#pragma unroll
    for (int p = 0; p < 8; p++) {
      int idx = t + 256*p;
      int r = idx >> 6, k = idx & 63;
      const int* nb = nbs + r*KNN;
      float s = 0.f;
#pragma unroll
      for (int j = 0; j < KNN; j++) s += h1b[nb[j]*64 + k];
      X[r*129 + 64 + k] = s;
    }

    int rg = t >> 5, cgi = t & 31;
    float acc[4][4];
#pragma unroll
    for (int r = 0; r < 4; r++)
#pragma unroll
      for (int u = 0; u < 4; u++) acc[r][u] = 0.f;

    const float* wsrc[4] = { a.g2wr, a.g2wr + 32*128, a.g2wl, a.g2wl + 32*128 };
#pragma unroll 1
    for (int ch = 0; ch < 4; ch++) {
      __syncthreads();
      const float* ws = wsrc[ch];
#pragma unroll
      for (int p = 0; p < 16; p++) {
        int idx = t + 256*p;
        Wt[idx] = ws[idx];
      }
      __syncthreads();
      int kb = ch * 32;
      const float* xr0 = X + (rg*4+0)*129 + kb;
      const float* xr1 = X + (rg*4+1)*129 + kb;
      const float* xr2 = X + (rg*4+2)*129 + kb;
      const float* xr3 = X + (rg*4+3)*129 + kb;
#pragma unroll 4
      for (int k = 0; k < 32; k++) {
        float4 w4 = *(const float4*)(Wt + k*128 + cgi*4);
        float x0 = xr0[k], x1 = xr1[k], x2 = xr2[k], x3 = xr3[k];
        acc[0][0] += x0*w4.x; acc[0][1] += x0*w4.y; acc[0][2] += x0*w4.z; acc[0][3] += x0*w4.w;
        acc[1][0] += x1*w4.x; acc[1][1] += x1*w4.y; acc[1][2] += x1*w4.z; acc[1][3] += x1*w4.w;
        acc[2][0] += x2*w4.x; acc[2][1] += x2*w4.y; acc[2][2] += x2*w4.z; acc[2][3] += x2*w4.w;
        acc[3][0] += x3*w4.x; acc[3][1] += x3*w4.y; acc[3][2] += x3*w4.z; acc[3][3] += x3*w4.w;
      }
    }
#pragma unroll
    for (int u = 0; u < 4; u++)
      mred[rg*128 + cgi*4 + u] =
        fmaxf(fmaxf(acc[0][u], acc[1][u]), fmaxf(acc[2][u], acc[3][u]));
    __syncthreads();
    if (t < 128) {
      float mx = mred[t];
#pragma unroll
      for (int g = 1; g < 8; g++) mx = fmaxf(mx, mred[g*128 + t]);
      stg_f(&a.pmax[(size_t)(b*16 + chunk)*128 + t], mx + a.g2b[t]);
    }
  }
  gbar(a.bar, 0, blk);

  // ------- phase 2: proxy max + kv (in-LDS, dup per block) + vv (384 blocks) --
  if (blk < 384) {
    int b = blk & 31, og = blk >> 5;              // og 0..11
    if (t < 128) {
      float m = -3e38f;
      for (int ch = 0; ch < 16; ch++)
        m = fmaxf(m, ldg_f(&a.pmax[(size_t)(b*16 + ch)*128 + t]));
      smem[t] = m;
    }
    __syncthreads();
    // kv (full 384) into smem[128..512); cheap dup across the 12 og-blocks
    for (int o = t; o < CC; o += 256) {
      float acc = a.projb[o];
      for (int s = 0; s < 128; s++) acc += smem[s] * a.projw[s*CC + o];  // coalesced
      smem[128 + o] = acc;
    }
    __syncthreads();
    const float* xs = smem + 128;
    int wv = t >> 6, lane = t & 63;
    float x0 = xs[lane*6+0], x1 = xs[lane*6+1], x2 = xs[lane*6+2];
    float x3 = xs[lane*6+3], x4 = xs[lane*6+4], x5 = xs[lane*6+5];
#pragma unroll
    for (int u = 0; u < 8; u++) {
      int o = og*32 + wv*8 + u;
      const float* wr = a.aiw + (size_t)(2*CC + o) * CC + lane*6;
      float2 wa = *(const float2*)wr;
      float2 wb = *(const float2*)(wr + 2);
      float2 wc = *(const float2*)(wr + 4);
      float p = wa.x*x0 + wa.y*x1 + wb.x*x2 + wb.y*x3 + wc.x*x4 + wc.y*x5;
      p = wave_sum(p);
      if (lane == 0) stg_f(&a.vv[b*CC + o], a.aib[2*CC + o] + p);
    }
  }
  gbar(a.bar, 1, blk);

  // ---------------- phase 3: q = vv @ aow.T + aob -> xcat[:,1024:] -----------
  if (blk < 384) {
    int b = blk & 31, og = blk >> 5;
    for (int i = t; i < CC; i += 256) smem[i] = ldg_f(&a.vv[b*CC + i]);
    __syncthreads();
    int wv = t >> 6, lane = t & 63;
    float x0 = smem[lane*6+0], x1 = smem[lane*6+1], x2 = smem[lane*6+2];
    float x3 = smem[lane*6+3], x4 = smem[lane*6+4], x5 = smem[lane*6+5];
#pragma unroll
    for (int u = 0; u < 8; u++) {
      int o = og*32 + wv*8 + u;
      const float* wr = a.aow + (size_t)o * CC + lane*6;
      float2 wa = *(const float2*)wr;
      float2 wb = *(const float2*)(wr + 2);
      float2 wc = *(const float2*)(wr + 4);
      float p = wa.x*x0 + wa.y*x1 + wb.x*x2 + wb.y*x3 + wc.x*x4 + wc.y*x5;
      p = wave_sum(p);
      if (lane == 0) stg_f(&a.xcat[b*1408 + 1024 + o], a.aob[o] + p);
    }
  }
  gbar(a.bar, 2, blk);

  // ---------------- phase 4: inc1 + BN + leaky (512 blocks) ------------------
  {
    int b = blk >> 4, og = blk & 15;
    int o = og*64 + (t >> 2), qq = t & 3;
    for (int i = t; i < CC; i += 256) smem[i] = ldg_f(&a.xcat[b*1408 + 1024 + i]);
    __syncthreads();
    const float* wr = a.i1w + (size_t)o * CC + qq*96;
    const float* xr = smem + qq*96;
    float acc = 0.f;
#pragma unroll
    for (int kk = 0; kk < 96; kk += 4) {
      float4 w4 = *(const float4*)(wr + kk);
      float4 x4 = *(const float4*)(xr + kk);
      acc += w4.x*x4.x + w4.y*x4.y + w4.z*x4.z + w4.w*x4.w;
    }
    acc += __shfl_xor(acc, 1, 64);
    acc += __shfl_xor(acc, 2, 64);
    if (qq == 0) {
      float v = acc + a.i1b[o];
      float z = a.bng[o] * (v - a.bnm[o]) * rsqrtf(a.bnv[o] + 1e-5f) + a.bnb[o];
      stg_f(&a.y[b*1024 + o], (z >= 0.f) ? z : 0.2f * z);
    }
  }
  gbar(a.bar, 3, blk);

  // ---------------- phase 5: inc2 -> xcat[:,0:1024] (512 blocks) -------------
  {
    int b = blk >> 4, og = blk & 15;
    int o = og*64 + (t >> 2), qq = t & 3;
    for (int i = t; i < 1024; i += 256) smem[i] = ldg_f(&a.y[b*1024 + i]);
    __syncthreads();
    const float* wr = a.i2w + (size_t)o * 1024 + qq*256;
    const float* xr = smem + qq*256;
    float acc = 0.f;
#pragma unroll 8
    for (int kk = 0; kk < 256; kk += 4) {
      float4 w4 = *(const float4*)(wr + kk);
      float4 x4 = *(const float4*)(xr + kk);
      acc += w4.x*x4.x + w4.y*x4.y + w4.z*x4.z + w4.w*x4.w;
    }
    acc += __shfl_xor(acc, 1, 64);
    acc += __shfl_xor(acc, 2, 64);
    if (qq == 0) stg_f(&a.xcat[b*1408 + o], acc + a.i2b[o]);
  }
  gbar(a.bar, 4, blk);

  // ---------------- phase 6: basep = xcat @ red_w[:1408] (48 blocks) ---------
  if (blk < 48) {
    int o0 = blk * 8;
    float* xs = smem;           // [32][129] chunk of xcat
    float* wt = smem + 4128;    // [128][8]  chunk of red_w
    int o4 = t & 1, bb = (t >> 1) & 31, kq = t >> 6;
    float acc0 = 0.f, acc1 = 0.f, acc2 = 0.f, acc3 = 0.f;
#pragma unroll 1
    for (int c0 = 0; c0 < 1408; c0 += 128) {
      __syncthreads();
#pragma unroll
      for (int p = 0; p < 16; p++) {
        int idx = t + 256*p;                    // 4096 = 32 b x 128 k
        xs[(idx >> 7)*129 + (idx & 127)] =
          ldg_f(&a.xcat[(idx >> 7)*1408 + c0 + (idx & 127)]);
      }
#pragma unroll
      for (int p = 0; p < 4; p++) {
        int idx = t + 256*p;                    // 1024 = 128 k x 8 o
        wt[idx] = a.redw[(size_t)(c0 + (idx >> 3)) * CC + o0 + (idx & 7)];
      }
      __syncthreads();
      const float* xrow = xs + bb*129 + kq*32;  // conflict-free (stride 129)
      const float* wrow = wt + kq*32*8 + o4*4;  // 2 distinct addrs/wave: broadcast
#pragma unroll 8
      for (int i = 0; i < 32; i++) {
        float  x  = xrow[i];
        float4 w4 = *(const float4*)(wrow + i*8);
        acc0 += x*w4.x; acc1 += x*w4.y; acc2 += x*w4.z; acc3 += x*w4.w;
      }
    }
    __syncthreads();
    float* red = smem;          // [256 threads][4]
    red[t*4+0] = acc0; red[t*4+1] = acc1; red[t*4+2] = acc2; red[t*4+3] = acc3;
    __syncthreads();
    {
      int bb2 = t >> 3, oj = t & 7;            // 32 b x 8 o
      float s = 0.f;
#pragma unroll
      for (int k2 = 0; k2 < 4; k2++)
        s += red[(k2*64 + bb2*2 + (oj >> 2))*4 + (oj & 3)];
      stg_f(&a.basep[bb2*CC + o0 + oj], s);
    }
  }
  gbar(a.bar, 5, blk);

  // ----- phase 7: out = basep + red_b + coarse @ red_w[1408:], 1 batch/block --
  {
    int b = blk >> 4, mg = blk & 15;            // 16 blocks per batch, 28 rows each
    for (int i = t; i < CC; i += 256) smem[i] = ldg_f(&a.basep[b*CC + i]);
    __syncthreads();
    const int m0 = mg * 28;
    for (int i = t; i < 28*96; i += 256) {
      int mr = i / 96, c4 = i - mr*96;
      int row = b*MM + m0 + mr;
      int c = c4 * 4;
      float4 p0 = *(const float4*)(smem + c);
      float4 rb = *(const float4*)(a.redb + c);
      const float* cr = a.coarse + (size_t)row * 3;
      float cx = cr[0], cy = cr[1], cz = cr[2];
      float4 w0 = *(const float4*)(a.redw + (size_t)1408*CC + c);
      float4 w1 = *(const float4*)(a.redw + (size_t)1409*CC + c);
      float4 w2 = *(const float4*)(a.redw + (size_t)1410*CC + c);
      float4 o4v;
      o4v.x = p0.x + rb.x + cx*w0.x + cy*w1.x + cz*w2.x;
      o4v.y = p0.y + rb.y + cx*w0.y + cy*w1.y + cz*w2.y;
      o4v.z = p0.z + rb.z + cx*w0.z + cy*w1.z + cz*w2.z;
      o4v.w = p0.w + rb.w + cx*w0.w + cy*w1.w + cz*w2.w;
      *(float4*)(a.out + (size_t)row*CC + c) = o4v;
    }
  }
}

extern "C" void kernel_launch(void* const* d_in, const int* in_sizes, int n_in,
                              void* d_out, int out_size, void* d_ws, size_t ws_size,
                              hipStream_t stream)
{
  (void)in_sizes; (void)n_in; (void)out_size; (void)ws_size;
  // d_in[0] is q (B,M,C): provably unused — attention softmax is uniform.
  const float* coarse = (const float*)d_in[1];
  const float* skel   = (const float*)d_in[2];
  const float* g1wr   = (const float*)d_in[3];
  const float* g1wl   = (const float*)d_in[4];
  const float* g1b    = (const float*)d_in[5];

  char* ws = (char*)d_ws;
  int*      idx_ws = (int*)(ws + WS_IDX);
  float*    h1_ws  = (float*)(ws + WS_H1);
  unsigned* bar    = (unsigned*)(ws + WS_BAR);

  CoopArgs a;
  a.h1    = h1_ws;
  a.idx   = idx_ws;
  a.g2wr  = (const float*)d_in[6];
  a.g2wl  = (const float*)d_in[7];
  a.g2b   = (const float*)d_in[8];
  a.projw = (const float*)d_in[9];
  a.projb = (const float*)d_in[10];
  a.aiw   = (const float*)d_in[11];
  a.aib   = (const float*)d_in[12];
  a.aow   = (const float*)d_in[13];
  a.aob   = (const float*)d_in[14];
  a.i1w   = (const float*)d_in[15];
  a.i1b   = (const float*)d_in[16];
  a.bng   = (const float*)d_in[17];
  a.bnb   = (const float*)d_in[18];
  a.bnm   = (const float*)d_in[19];
  a.bnv   = (const float*)d_in[20];
  a.i2w   = (const float*)d_in[21];
  a.i2b   = (const float*)d_in[22];
  a.redw  = (const float*)d_in[23];
  a.redb  = (const float*)d_in[24];
  a.coarse= coarse;
  a.pmax  = (float*)(ws + WS_PMAX);
  a.vv    = (float*)(ws + WS_VV);
  a.y     = (float*)(ws + WS_Y);
  a.xcat  = (float*)(ws + WS_XCAT);
  a.basep = (float*)(ws + WS_BASEP);
  a.out   = (float*)d_out;
  a.bar   = bar;

  k_knn_gc1<<<4096, 256, 0, stream>>>(skel, g1wr, g1wl, g1b, idx_ws, h1_ws, bar);
  k_fused<<<NBLK, 256, 0, stream>>>(a);
}